// Round 3
// baseline (260.211 us; speedup 1.0000x reference)
//
#include <hip/hip_runtime.h>
#include <hip/hip_bf16.h>

// MultiheadAttention: B=8, T=S=1024, n_heads=8, d_head=128, D=1024.
// Device buffer dtype (fp32 vs bf16) is DETECTED at runtime (k_detect) and all
// inputs are converted into canonical bf16 ws buffers. Pipeline:
//   D:  detect input dtype -> flag in ws
//   C1: q/k/v -> canonical bf16 Xq/Xk/Xv
//   C2: weights (transposed) + biases -> canonical bf16
//   K1: QKV projection GEMM -> Qp/Kp [b][h][t][d], VpT [b][h][d][t] (bf16)
//       (Q scaled by log2e/sqrt(128) so flash uses exp2)
//   K2: causal flash attention -> O [b][t][h*128+d] (bf16)
//   K3: out-proj split-K=4 -> fp32 ws accumulator (deterministic)
//   K4: sum slices + bias -> d_out (fp32 or bf16 per flag)

typedef __attribute__((ext_vector_type(8))) short short8;
typedef __attribute__((ext_vector_type(4))) short short4v;
typedef __attribute__((ext_vector_type(4))) float f32x4;

#define B_   8
#define S_   1024
#define DH_  128
#define NH_  8
#define DM_  1024  // NH_*DH_

#define MFMA16(a, b, c) __builtin_amdgcn_mfma_f32_16x16x32_bf16((a), (b), (c), 0, 0, 0)

__device__ __forceinline__ float bf2f(unsigned short u) {
  union { unsigned int i; float f; } x; x.i = ((unsigned int)u) << 16; return x.f;
}
__device__ __forceinline__ unsigned short f2bf(float f) {
  union { float f; unsigned int i; } x; x.f = f;
  unsigned int r = (x.i + 0x7fffu + ((x.i >> 16) & 1u)) >> 16;
  return (unsigned short)r;
}
// read element i of a buffer whose dtype is selected by fp flag
__device__ __forceinline__ float ldany(const void* p, int i, int fp) {
  return fp ? ((const float*)p)[i] : bf2f(((const unsigned short*)p)[i]);
}

// ---------------- D: input dtype detection ----------------
// Legit bf16 N(0,1) data never has exp==0xFF or nonzero denormals; fp32 data
// read as halfwords has random mantissa words -> triggers w.p. ~1-e^-64.
__global__ void k_detect(const unsigned short* __restrict__ in, int* __restrict__ flag) {
  __shared__ int f;
  int tid = threadIdx.x;
  if (tid == 0) f = 0;
  __syncthreads();
  int t = 0;
  for (int i = tid; i < 16384; i += 256) {  // 32 KB: safe under either dtype
    unsigned h = in[i];
    unsigned e = (h >> 7) & 0xFFu, m = h & 0x7Fu;
    if (e == 0xFFu || (e == 0u && m != 0u)) t = 1;
  }
  if (t) atomicOr(&f, 1);
  __syncthreads();
  if (tid == 0) *flag = f;  // 1 = fp32, 0 = bf16
}

// ---------------- C1: q/k/v -> canonical bf16 ----------------
// grid (4096, 3) x 256 : exactly 1048576 elements per tensor
__global__ void k_cvt_x(const void* __restrict__ q, const void* __restrict__ k,
                        const void* __restrict__ v, const int* __restrict__ flag,
                        unsigned short* __restrict__ Xq, unsigned short* __restrict__ Xk,
                        unsigned short* __restrict__ Xv) {
  const int fp = *flag;
  int z = blockIdx.y;
  const void* in = (z == 0) ? q : (z == 1) ? k : v;
  unsigned short* out = (z == 0) ? Xq : (z == 1) ? Xk : Xv;
  int e = blockIdx.x * 256 + threadIdx.x;
  out[e] = fp ? f2bf(((const float*)in)[e]) : ((const unsigned short*)in)[e];
}

// ---------------- C2: weights (transposed) + biases -> canonical bf16 ----------------
// grid (2061, 1) x 256, flat index over 527488 jobs
__global__ void k_cvt_w(const void* __restrict__ Wq, const void* __restrict__ Wk,
                        const void* __restrict__ Wv, const void* __restrict__ Wo,
                        const void* __restrict__ bq, const void* __restrict__ bk,
                        const void* __restrict__ bv, const void* __restrict__ bo,
                        const int* __restrict__ flag,
                        unsigned short* __restrict__ wqT, unsigned short* __restrict__ wkT,
                        unsigned short* __restrict__ wvT, unsigned short* __restrict__ woT,
                        unsigned short* __restrict__ bqc, unsigned short* __restrict__ bkc,
                        unsigned short* __restrict__ bvc, unsigned short* __restrict__ boc) {
  const int fp = *flag;
  int g = blockIdx.x * 256 + threadIdx.x;
  if (g < 393216) {  // Wq/Wk/Wv [128][1024] -> [1024][128]
    int z = g >> 17, e = g & 131071;
    const void* in = (z == 0) ? Wq : (z == 1) ? Wk : Wv;
    unsigned short* out = (z == 0) ? wqT : (z == 1) ? wkT : wvT;
    int r = e >> 10, c = e & 1023;
    out[c * 128 + r] = f2bf(ldany(in, e, fp));
  } else if (g < 524288) {  // Wo [1024][128] -> [128][1024]
    int e = g - 393216;
    int r = e >> 7, c = e & 127;
    woT[c * 1024 + r] = f2bf(ldany(Wo, e, fp));
  } else if (g < 525312) {
    int e = g - 524288; bqc[e] = f2bf(ldany(bq, e, fp));
  } else if (g < 526336) {
    int e = g - 525312; bkc[e] = f2bf(ldany(bk, e, fp));
  } else if (g < 527360) {
    int e = g - 526336; bvc[e] = f2bf(ldany(bv, e, fp));
  } else if (g < 527488) {
    int e = g - 527360; boc[e] = f2bf(ldany(bo, e, fp));
  }
}

// ---------------- K1: fused QKV projection GEMM ----------------
// grid (64, 8, 3), block 256 (4 waves, 2x2 of 64x64). M=8192,K=128,N=1024.
__global__ __launch_bounds__(256) void k_qkv(
    const unsigned short* __restrict__ Xq, const unsigned short* __restrict__ Xk,
    const unsigned short* __restrict__ Xv,
    const unsigned short* __restrict__ WqT, const unsigned short* __restrict__ WkT,
    const unsigned short* __restrict__ WvT,
    const unsigned short* __restrict__ bq, const unsigned short* __restrict__ bk,
    const unsigned short* __restrict__ bv,
    unsigned short* __restrict__ Qp, unsigned short* __restrict__ Kp,
    unsigned short* __restrict__ VpT) {
  __shared__ unsigned short vtile[128][136];  // V epilogue transpose tile (+8 pad)

  const int mat = blockIdx.z;
  const unsigned short* X    = (mat == 0) ? Xq  : (mat == 1) ? Xk  : Xv;
  const unsigned short* WT   = (mat == 0) ? WqT : (mat == 1) ? WkT : WvT;
  const unsigned short* bias = (mat == 0) ? bq  : (mat == 1) ? bk  : bv;
  // fold softmax scale AND log2(e) into Q so flash uses exp2
  const float scale = (mat == 0) ? (1.4426950408889634f / 11.313708498984761f) : 1.0f;

  const int tid = threadIdx.x, lane = tid & 63, wave = tid >> 6;
  const int wm = wave >> 1, wn = wave & 1;
  const int l15 = lane & 15, lg = lane >> 4;
  const int mbase = blockIdx.x * 128 + wm * 64;
  const int nbase = blockIdx.y * 128 + wn * 64;

  short8 a[4][4];
#pragma unroll
  for (int mi = 0; mi < 4; ++mi)
#pragma unroll
    for (int kk = 0; kk < 4; ++kk)
      a[mi][kk] = *(const short8*)&X[(mbase + mi * 16 + l15) * DH_ + kk * 32 + lg * 8];

  f32x4 acc[4][4];
#pragma unroll
  for (int mi = 0; mi < 4; ++mi)
#pragma unroll
    for (int ni = 0; ni < 4; ++ni) acc[mi][ni] = (f32x4){0.f, 0.f, 0.f, 0.f};

#pragma unroll
  for (int ni = 0; ni < 4; ++ni) {
    short8 bfr[4];
#pragma unroll
    for (int kk = 0; kk < 4; ++kk)
      bfr[kk] = *(const short8*)&WT[(nbase + ni * 16 + l15) * DH_ + kk * 32 + lg * 8];
#pragma unroll
    for (int mi = 0; mi < 4; ++mi)
#pragma unroll
      for (int kk = 0; kk < 4; ++kk)
        acc[mi][ni] = MFMA16(a[mi][kk], bfr[kk], acc[mi][ni]);
  }

  if (mat < 2) {
    unsigned short* Out = (mat == 0) ? Qp : Kp;
#pragma unroll
    for (int mi = 0; mi < 4; ++mi)
#pragma unroll
      for (int ni = 0; ni < 4; ++ni) {
        int n = nbase + ni * 16 + l15;
        float bv_ = bf2f(bias[n]);
        int h = n >> 7, dh = n & 127;
#pragma unroll
        for (int reg = 0; reg < 4; ++reg) {
          int m = mbase + mi * 16 + lg * 4 + reg;
          int b = m >> 10, t = m & 1023;
          float val = (acc[mi][ni][reg] + bv_) * scale;
          Out[((b * NH_ + h) * S_ + t) * DH_ + dh] = f2bf(val);
        }
      }
  } else {
    // V: stage C tile in LDS, write transposed [b][h][d][t]
#pragma unroll
    for (int mi = 0; mi < 4; ++mi)
#pragma unroll
      for (int ni = 0; ni < 4; ++ni) {
        int nl = wn * 64 + ni * 16 + l15;
        float bv_ = bf2f(bias[blockIdx.y * 128 + nl]);
#pragma unroll
        for (int reg = 0; reg < 4; ++reg) {
          int ml = wm * 64 + mi * 16 + lg * 4 + reg;
          vtile[ml][nl] = f2bf(acc[mi][ni][reg] + bv_);
        }
      }
    __syncthreads();
    int n = tid >> 1;              // dh 0..127
    int thalf = (tid & 1) * 64;    // t-half within the 128-row m tile
    int b = blockIdx.x >> 3;       // 8 m-blocks per batch
    int h = blockIdx.y;            // BN=128 == one head
    int base = ((b * NH_ + h) * DH_ + n) * S_ + (blockIdx.x & 7) * 128 + thalf;
#pragma unroll
    for (int jj = 0; jj < 8; ++jj) {
      short8 v;
#pragma unroll
      for (int j2 = 0; j2 < 8; ++j2) v[j2] = (short)vtile[thalf + jj * 8 + j2][n];
      *(short8*)&VpT[base + jj * 8] = v;
    }
  }
}

// ---------------- K2: causal flash attention ----------------
// grid (8, 64) = (q-tile, b*h), block 256 = 4 independent waves (no barriers).
__global__ __launch_bounds__(256) void k_attn(
    const unsigned short* __restrict__ Qp, const unsigned short* __restrict__ Kp,
    const unsigned short* __restrict__ VpT, unsigned short* __restrict__ O) {
  __shared__ __align__(16) unsigned short plds[4][2][16][40];

  const int qt = 7 - blockIdx.x;
  const int bh = blockIdx.y;
  const int tid = threadIdx.x, lane = tid & 63, w = tid >> 6;
  const int l15 = lane & 15, lg = lane >> 4;
  const int q0 = qt * 128 + w * 32;

  const unsigned short* Qb = Qp + bh * (S_ * DH_);
  const unsigned short* Kb = Kp + bh * (S_ * DH_);
  const unsigned short* Vb = VpT + bh * (DH_ * S_);

  short8 qf[2][4];
#pragma unroll
  for (int mi = 0; mi < 2; ++mi)
#pragma unroll
    for (int kk = 0; kk < 4; ++kk)
      qf[mi][kk] = *(const short8*)&Qb[(q0 + mi * 16 + l15) * DH_ + kk * 32 + lg * 8];

  f32x4 of[2][8];
  float m_[2][4], l_[2][4];
#pragma unroll
  for (int mi = 0; mi < 2; ++mi) {
#pragma unroll
    for (int di = 0; di < 8; ++di) of[mi][di] = (f32x4){0.f, 0.f, 0.f, 0.f};
#pragma unroll
    for (int reg = 0; reg < 4; ++reg) { m_[mi][reg] = -1e30f; l_[mi][reg] = 0.f; }
  }

  const int ntiles = q0 / 32 + 1;
  for (int kt = 0; kt < ntiles; ++kt) {
    const int sb = kt * 32;
    const bool lastt = (kt == ntiles - 1);

    f32x4 s[2][2];
#pragma unroll
    for (int mi = 0; mi < 2; ++mi)
#pragma unroll
      for (int ni = 0; ni < 2; ++ni) s[mi][ni] = (f32x4){0.f, 0.f, 0.f, 0.f};
#pragma unroll
    for (int ni = 0; ni < 2; ++ni) {
      short8 kf[4];
#pragma unroll
      for (int kk = 0; kk < 4; ++kk)
        kf[kk] = *(const short8*)&Kb[(sb + ni * 16 + l15) * DH_ + kk * 32 + lg * 8];
#pragma unroll
      for (int mi = 0; mi < 2; ++mi)
#pragma unroll
        for (int kk = 0; kk < 4; ++kk)
          s[mi][ni] = MFMA16(qf[mi][kk], kf[kk], s[mi][ni]);
    }

#pragma unroll
    for (int mi = 0; mi < 2; ++mi) {
      float alpha[4];
#pragma unroll
      for (int reg = 0; reg < 4; ++reg) {
        int q = q0 + mi * 16 + lg * 4 + reg;
        float v0 = s[mi][0][reg];
        float v1 = s[mi][1][reg];
        if (lastt) {
          if (sb + l15 > q)      v0 = -1e30f;
          if (sb + 16 + l15 > q) v1 = -1e30f;
        }
        float r = fmaxf(v0, v1);
#pragma unroll
        for (int d = 1; d < 16; d <<= 1) r = fmaxf(r, __shfl_xor(r, d));
        float mn = fmaxf(m_[mi][reg], r);
        alpha[reg] = exp2f(m_[mi][reg] - mn);
        m_[mi][reg] = mn;
        float p0 = exp2f(v0 - mn), p1 = exp2f(v1 - mn);
        float rs = p0 + p1;
#pragma unroll
        for (int d = 1; d < 16; d <<= 1) rs += __shfl_xor(rs, d);
        l_[mi][reg] = l_[mi][reg] * alpha[reg] + rs;
        plds[w][mi][lg * 4 + reg][l15]      = f2bf(p0);
        plds[w][mi][lg * 4 + reg][16 + l15] = f2bf(p1);
      }
#pragma unroll
      for (int di = 0; di < 8; ++di)
#pragma unroll
        for (int reg = 0; reg < 4; ++reg) of[mi][di][reg] *= alpha[reg];
    }

    short8 pa[2];
#pragma unroll
    for (int mi = 0; mi < 2; ++mi)
      pa[mi] = *(const short8*)&plds[w][mi][l15][lg * 8];

#pragma unroll
    for (int di = 0; di < 8; ++di) {
      short8 vf = *(const short8*)&Vb[(di * 16 + l15) * S_ + sb + lg * 8];
#pragma unroll
      for (int mi = 0; mi < 2; ++mi) of[mi][di] = MFMA16(pa[mi], vf, of[mi][di]);
    }
  }

  const int b = bh >> 3, h = bh & 7;
#pragma unroll
  for (int mi = 0; mi < 2; ++mi)
#pragma unroll
    for (int reg = 0; reg < 4; ++reg) {
      float inv = 1.0f / l_[mi][reg];
      int q = q0 + mi * 16 + lg * 4 + reg;
#pragma unroll
      for (int di = 0; di < 8; ++di) {
        int d = di * 16 + l15;
        O[(b * S_ + q) * DM_ + h * DH_ + d] = f2bf(of[mi][di][reg] * inv);
      }
    }
}

// ---------------- K3: out-proj split-K GEMM ----------------
__global__ __launch_bounds__(256) void k_oproj(
    const unsigned short* __restrict__ O, const unsigned short* __restrict__ WoT,
    float* __restrict__ outacc) {
  const int tid = threadIdx.x, lane = tid & 63, wave = tid >> 6;
  const int wm = wave >> 1, wn = wave & 1;
  const int l15 = lane & 15, lg = lane >> 4;
  const int mbase = blockIdx.x * 128 + wm * 64;
  const int kc = blockIdx.y;

  f32x4 acc[4][4];
#pragma unroll
  for (int mi = 0; mi < 4; ++mi)
#pragma unroll
    for (int ni = 0; ni < 4; ++ni) acc[mi][ni] = (f32x4){0.f, 0.f, 0.f, 0.f};

  for (int ks = 0; ks < 8; ++ks) {
    int kb = kc * 256 + ks * 32;
    short8 a[4], bfr[4];
#pragma unroll
    for (int mi = 0; mi < 4; ++mi)
      a[mi] = *(const short8*)&O[(mbase + mi * 16 + l15) * DM_ + kb + lg * 8];
#pragma unroll
    for (int ni = 0; ni < 4; ++ni)
      bfr[ni] = *(const short8*)&WoT[(wn * 64 + ni * 16 + l15) * DM_ + kb + lg * 8];
#pragma unroll
    for (int mi = 0; mi < 4; ++mi)
#pragma unroll
      for (int ni = 0; ni < 4; ++ni) acc[mi][ni] = MFMA16(a[mi], bfr[ni], acc[mi][ni]);
  }

  float* oa = outacc + kc * (8192 * 128);
#pragma unroll
  for (int mi = 0; mi < 4; ++mi)
#pragma unroll
    for (int ni = 0; ni < 4; ++ni) {
      int n = wn * 64 + ni * 16 + l15;
#pragma unroll
      for (int reg = 0; reg < 4; ++reg) {
        int m = mbase + mi * 16 + lg * 4 + reg;
        oa[m * 128 + n] = acc[mi][ni][reg];
      }
    }
}

// ---------------- K4: reduce split-K + bias -> out (dtype per flag) ----------------
__global__ void k_final(const float* __restrict__ outacc,
                        const unsigned short* __restrict__ boc,
                        const int* __restrict__ flag, void* __restrict__ out) {
  int i4 = (blockIdx.x * 256 + threadIdx.x) * 4;
  f32x4 v = *(const f32x4*)&outacc[i4];
  v += *(const f32x4*)&outacc[1048576 + i4];
  v += *(const f32x4*)&outacc[2097152 + i4];
  v += *(const f32x4*)&outacc[3145728 + i4];
  int n0 = i4 & 127;
#pragma unroll
  for (int j = 0; j < 4; ++j) v[j] += bf2f(boc[n0 + j]);
  if (*flag) {
    *(f32x4*)&((float*)out)[i4] = v;
  } else {
    short4v o;
#pragma unroll
    for (int j = 0; j < 4; ++j) o[j] = (short)f2bf(v[j]);
    *(short4v*)&((unsigned short*)out)[i4] = o;
  }
}

extern "C" void kernel_launch(void* const* d_in, const int* in_sizes, int n_in,
                              void* d_out, int out_size, void* d_ws, size_t ws_size,
                              hipStream_t stream) {
  const void* q  = d_in[0];
  const void* k  = d_in[1];
  const void* v  = d_in[2];
  const void* Wq = d_in[3];
  const void* bq = d_in[4];
  const void* Wk = d_in[5];
  const void* bk = d_in[6];
  const void* Wv = d_in[7];
  const void* bv = d_in[8];
  const void* Wo = d_in[9];
  const void* bo = d_in[10];

  char* ws = (char*)d_ws;
  int*            flag = (int*)(ws + 0);
  unsigned short* wqT  = (unsigned short*)(ws + 4096);      // [1024][128] 256 KB
  unsigned short* wkT  = (unsigned short*)(ws + 266240);
  unsigned short* wvT  = (unsigned short*)(ws + 528384);
  unsigned short* woT  = (unsigned short*)(ws + 790528);    // [128][1024] 256 KB
  unsigned short* bqc  = (unsigned short*)(ws + 1052672);
  unsigned short* bkc  = (unsigned short*)(ws + 1054720);
  unsigned short* bvc  = (unsigned short*)(ws + 1056768);
  unsigned short* boc  = (unsigned short*)(ws + 1058816);
  unsigned short* Xq   = (unsigned short*)(ws + 2097152);   // 2 MB [8192][128]
  unsigned short* Xk   = (unsigned short*)(ws + 4194304);   // 2 MB
  unsigned short* Xv   = (unsigned short*)(ws + 6291456);   // 2 MB
  unsigned short* Qp   = (unsigned short*)(ws + 8388608);   // 16 MB [b][h][t][d]
  unsigned short* Kp   = (unsigned short*)(ws + 25165824);  // 16 MB [b][h][t][d]
  unsigned short* VpT  = (unsigned short*)(ws + 41943040);  // 16 MB [b][h][d][t]
  unsigned short* O    = (unsigned short*)(ws + 58720256);  // 16 MB [b][t][h*d]
  float*          oacc = (float*)(ws + 75497472);           // 16 MB fp32 x4 slices

  k_detect<<<dim3(1), 256, 0, stream>>>((const unsigned short*)q, flag);
  k_cvt_x<<<dim3(4096, 3), 256, 0, stream>>>(q, k, v, flag, Xq, Xk, Xv);
  k_cvt_w<<<dim3(2061), 256, 0, stream>>>(Wq, Wk, Wv, Wo, bq, bk, bv, bo, flag,
                                          wqT, wkT, wvT, woT, bqc, bkc, bvc, boc);
  k_qkv<<<dim3(64, 8, 3), 256, 0, stream>>>(Xq, Xk, Xv, wqT, wkT, wvT, bqc, bkc, bvc,
                                            Qp, Kp, VpT);
  k_attn<<<dim3(8, 64), 256, 0, stream>>>(Qp, Kp, VpT, O);
  k_oproj<<<dim3(64, 4), 256, 0, stream>>>(O, woT, oacc);
  k_final<<<dim3(1024), 256, 0, stream>>>(oacc, boc, flag, d_out);
}

// Round 4
// 194.593 us; speedup vs baseline: 1.3372x; 1.3372x over previous
//
#include <hip/hip_runtime.h>
#include <hip/hip_bf16.h>

// MultiheadAttention: B=8, T=S=1024, n_heads=8, d_head=128, D=1024.
// Device buffer dtype (fp32 vs bf16) detected at runtime; all inputs converted
// to canonical bf16 ws buffers. Pipeline:
//   D:  detect input dtype -> flag in ws
//   C1: q/k/v -> canonical bf16 (vectorized x4)
//   C2: weights (transposed) + biases -> canonical bf16
//   K1: QKV projection GEMM -> Qp/Kp [b][h][t][d], VpT [b][h][d][t] (bf16)
//   K2: causal flash attention, SPLIT-S uniform work units (5120 waves,
//       <=8 s-tiles each) -> fp16 normalized partials + (m,l); row-sum via
//       ones-MFMA (no sum shuffle chain); V loads hoisted over softmax.
//   K2b: deterministic combine of <=4 partials -> O bf16
//   (fallback single-pass k_attn if ws_size too small for partials)
//   K3: out-proj split-K=4 -> fp32 ws accumulator
//   K4: sum slices + bias -> d_out (fp32 or bf16 per flag)

typedef __attribute__((ext_vector_type(8))) short short8;
typedef __attribute__((ext_vector_type(4))) short short4v;
typedef __attribute__((ext_vector_type(4))) float f32x4;

#define B_   8
#define S_   1024
#define DH_  128
#define NH_  8
#define DM_  1024

#define MFMA16(a, b, c) __builtin_amdgcn_mfma_f32_16x16x32_bf16((a), (b), (c), 0, 0, 0)

__device__ __forceinline__ float bf2f(unsigned short u) {
  union { unsigned int i; float f; } x; x.i = ((unsigned int)u) << 16; return x.f;
}
__device__ __forceinline__ unsigned short f2bf(float f) {
  union { float f; unsigned int i; } x; x.f = f;
  unsigned int r = (x.i + 0x7fffu + ((x.i >> 16) & 1u)) >> 16;
  return (unsigned short)r;
}
__device__ __forceinline__ unsigned short f2h(float f) {
  union { _Float16 h; unsigned short u; } x; x.h = (_Float16)f; return x.u;
}
__device__ __forceinline__ float h2f(unsigned short u) {
  union { unsigned short u; _Float16 h; } x; x.u = u; return (float)x.h;
}
__device__ __forceinline__ float ldany(const void* p, int i, int fp) {
  return fp ? ((const float*)p)[i] : bf2f(((const unsigned short*)p)[i]);
}

// ---------------- D: input dtype detection ----------------
__global__ void k_detect(const unsigned short* __restrict__ in, int* __restrict__ flag) {
  __shared__ int f;
  int tid = threadIdx.x;
  if (tid == 0) f = 0;
  __syncthreads();
  int t = 0;
  for (int i = tid; i < 16384; i += 256) {
    unsigned h = in[i];
    unsigned e = (h >> 7) & 0xFFu, m = h & 0x7Fu;
    if (e == 0xFFu || (e == 0u && m != 0u)) t = 1;
  }
  if (t) atomicOr(&f, 1);
  __syncthreads();
  if (tid == 0) *flag = f;  // 1 = fp32, 0 = bf16
}

// ---------------- C1: q/k/v -> canonical bf16 (x4 vectorized) ----------------
__global__ void k_cvt_x(const void* __restrict__ q, const void* __restrict__ k,
                        const void* __restrict__ v, const int* __restrict__ flag,
                        unsigned short* __restrict__ Xq, unsigned short* __restrict__ Xk,
                        unsigned short* __restrict__ Xv) {
  const int fp = *flag;
  int z = blockIdx.y;
  const void* in = (z == 0) ? q : (z == 1) ? k : v;
  unsigned short* out = (z == 0) ? Xq : (z == 1) ? Xk : Xv;
  int e4 = (blockIdx.x * 256 + threadIdx.x) * 4;  // 1048576 elems / tensor
  if (fp) {
    f32x4 x = *(const f32x4*)&((const float*)in)[e4];
    short4v o;
#pragma unroll
    for (int j = 0; j < 4; ++j) o[j] = (short)f2bf(x[j]);
    *(short4v*)&out[e4] = o;
  } else {
    *(short4v*)&out[e4] = *(const short4v*)&((const unsigned short*)in)[e4];
  }
}

// ---------------- C2: weights (transposed) + biases -> canonical bf16 ----------------
__global__ void k_cvt_w(const void* __restrict__ Wq, const void* __restrict__ Wk,
                        const void* __restrict__ Wv, const void* __restrict__ Wo,
                        const void* __restrict__ bq, const void* __restrict__ bk,
                        const void* __restrict__ bv, const void* __restrict__ bo,
                        const int* __restrict__ flag,
                        unsigned short* __restrict__ wqT, unsigned short* __restrict__ wkT,
                        unsigned short* __restrict__ wvT, unsigned short* __restrict__ woT,
                        unsigned short* __restrict__ bqc, unsigned short* __restrict__ bkc,
                        unsigned short* __restrict__ bvc, unsigned short* __restrict__ boc) {
  const int fp = *flag;
  int g = blockIdx.x * 256 + threadIdx.x;
  if (g < 393216) {  // Wq/Wk/Wv [128][1024] -> [1024][128]
    int z = g >> 17, e = g & 131071;
    const void* in = (z == 0) ? Wq : (z == 1) ? Wk : Wv;
    unsigned short* out = (z == 0) ? wqT : (z == 1) ? wkT : wvT;
    int r = e >> 10, c = e & 1023;
    out[c * 128 + r] = f2bf(ldany(in, e, fp));
  } else if (g < 524288) {  // Wo [1024][128] -> [128][1024]
    int e = g - 393216;
    int r = e >> 7, c = e & 127;
    woT[c * 1024 + r] = f2bf(ldany(Wo, e, fp));
  } else if (g < 525312) {
    int e = g - 524288; bqc[e] = f2bf(ldany(bq, e, fp));
  } else if (g < 526336) {
    int e = g - 525312; bkc[e] = f2bf(ldany(bk, e, fp));
  } else if (g < 527360) {
    int e = g - 526336; bvc[e] = f2bf(ldany(bv, e, fp));
  } else if (g < 527488) {
    int e = g - 527360; boc[e] = f2bf(ldany(bo, e, fp));
  }
}

// ---------------- K1: fused QKV projection GEMM ----------------
__global__ __launch_bounds__(256) void k_qkv(
    const unsigned short* __restrict__ Xq, const unsigned short* __restrict__ Xk,
    const unsigned short* __restrict__ Xv,
    const unsigned short* __restrict__ WqT, const unsigned short* __restrict__ WkT,
    const unsigned short* __restrict__ WvT,
    const unsigned short* __restrict__ bq, const unsigned short* __restrict__ bk,
    const unsigned short* __restrict__ bv,
    unsigned short* __restrict__ Qp, unsigned short* __restrict__ Kp,
    unsigned short* __restrict__ VpT) {
  __shared__ unsigned short vtile[128][136];

  const int mat = blockIdx.z;
  const unsigned short* X    = (mat == 0) ? Xq  : (mat == 1) ? Xk  : Xv;
  const unsigned short* WT   = (mat == 0) ? WqT : (mat == 1) ? WkT : WvT;
  const unsigned short* bias = (mat == 0) ? bq  : (mat == 1) ? bk  : bv;
  const float scale = (mat == 0) ? (1.4426950408889634f / 11.313708498984761f) : 1.0f;

  const int tid = threadIdx.x, lane = tid & 63, wave = tid >> 6;
  const int wm = wave >> 1, wn = wave & 1;
  const int l15 = lane & 15, lg = lane >> 4;
  const int mbase = blockIdx.x * 128 + wm * 64;
  const int nbase = blockIdx.y * 128 + wn * 64;

  short8 a[4][4];
#pragma unroll
  for (int mi = 0; mi < 4; ++mi)
#pragma unroll
    for (int kk = 0; kk < 4; ++kk)
      a[mi][kk] = *(const short8*)&X[(mbase + mi * 16 + l15) * DH_ + kk * 32 + lg * 8];

  f32x4 acc[4][4];
#pragma unroll
  for (int mi = 0; mi < 4; ++mi)
#pragma unroll
    for (int ni = 0; ni < 4; ++ni) acc[mi][ni] = (f32x4){0.f, 0.f, 0.f, 0.f};

#pragma unroll
  for (int ni = 0; ni < 4; ++ni) {
    short8 bfr[4];
#pragma unroll
    for (int kk = 0; kk < 4; ++kk)
      bfr[kk] = *(const short8*)&WT[(nbase + ni * 16 + l15) * DH_ + kk * 32 + lg * 8];
#pragma unroll
    for (int mi = 0; mi < 4; ++mi)
#pragma unroll
      for (int kk = 0; kk < 4; ++kk)
        acc[mi][ni] = MFMA16(a[mi][kk], bfr[kk], acc[mi][ni]);
  }

  if (mat < 2) {
    unsigned short* Out = (mat == 0) ? Qp : Kp;
#pragma unroll
    for (int mi = 0; mi < 4; ++mi)
#pragma unroll
      for (int ni = 0; ni < 4; ++ni) {
        int n = nbase + ni * 16 + l15;
        float bv_ = bf2f(bias[n]);
        int h = n >> 7, dh = n & 127;
#pragma unroll
        for (int reg = 0; reg < 4; ++reg) {
          int m = mbase + mi * 16 + lg * 4 + reg;
          int b = m >> 10, t = m & 1023;
          float val = (acc[mi][ni][reg] + bv_) * scale;
          Out[((b * NH_ + h) * S_ + t) * DH_ + dh] = f2bf(val);
        }
      }
  } else {
#pragma unroll
    for (int mi = 0; mi < 4; ++mi)
#pragma unroll
      for (int ni = 0; ni < 4; ++ni) {
        int nl = wn * 64 + ni * 16 + l15;
        float bv_ = bf2f(bias[blockIdx.y * 128 + nl]);
#pragma unroll
        for (int reg = 0; reg < 4; ++reg) {
          int ml_ = wm * 64 + mi * 16 + lg * 4 + reg;
          vtile[ml_][nl] = f2bf(acc[mi][ni][reg] + bv_);
        }
      }
    __syncthreads();
    int n = tid >> 1;
    int thalf = (tid & 1) * 64;
    int b = blockIdx.x >> 3;
    int h = blockIdx.y;
    int base = ((b * NH_ + h) * DH_ + n) * S_ + (blockIdx.x & 7) * 128 + thalf;
#pragma unroll
    for (int jj = 0; jj < 8; ++jj) {
      short8 v;
#pragma unroll
      for (int j2 = 0; j2 < 8; ++j2) v[j2] = (short)vtile[thalf + jj * 8 + j2][n];
      *(short8*)&VpT[base + jj * 8] = v;
    }
  }
}

// ---------------- K2: split-S causal flash attention ----------------
// 5120 uniform wave-units: (bh 0..63) x (80 units: qw 0..31, chunk c of 256 s).
// Each wave: <=8 KBLK=32 tiles, online softmax, ones-MFMA row sums,
// writes fp16 normalized partial O + (m,l) fp32.
__global__ __launch_bounds__(256) void k_attn_split(
    const unsigned short* __restrict__ Qp, const unsigned short* __restrict__ Kp,
    const unsigned short* __restrict__ VpT,
    unsigned short* __restrict__ Opart, float* __restrict__ ml) {
  __shared__ __align__(16) unsigned short plds[4][2][16][40];

  const int tid = threadIdx.x, lane = tid & 63, w = tid >> 6;
  const int l15 = lane & 15, lg = lane >> 4;
  const int g = blockIdx.x * 4 + w;       // 0..5119
  const int bh = g / 80;
  const int r = g % 80;
  int qw, c;
  if (r < 8)       { qw = r;                 c = 0; }
  else if (r < 24) { qw = 8 + ((r - 8) >> 1);  c = (r - 8) & 1; }
  else if (r < 48) { qw = 16 + (r - 24) / 3;   c = (r - 24) % 3; }
  else             { qw = 24 + ((r - 48) >> 2); c = (r - 48) & 3; }
  const int q0 = qw * 32;
  const int nc = (qw >> 3) + 1;
  const int sbeg = c * 256;
  const int send = (c == nc - 1) ? (q0 + 32) : (sbeg + 256);
  const int nt = (send - sbeg) >> 5;

  const unsigned short* Qb = Qp + bh * (S_ * DH_);
  const unsigned short* Kb = Kp + bh * (S_ * DH_);
  const unsigned short* Vb = VpT + bh * (DH_ * S_);

  short8 qf[2][4];
#pragma unroll
  for (int mi = 0; mi < 2; ++mi)
#pragma unroll
    for (int kk = 0; kk < 4; ++kk)
      qf[mi][kk] = *(const short8*)&Qb[(q0 + mi * 16 + l15) * DH_ + kk * 32 + lg * 8];

  short8 ones;
#pragma unroll
  for (int j = 0; j < 8; ++j) ones[j] = (short)0x3F80;  // bf16 1.0

  f32x4 of[2][8], l_acc[2];
  float m_[2][4];
#pragma unroll
  for (int mi = 0; mi < 2; ++mi) {
#pragma unroll
    for (int di = 0; di < 8; ++di) of[mi][di] = (f32x4){0.f, 0.f, 0.f, 0.f};
    l_acc[mi] = (f32x4){0.f, 0.f, 0.f, 0.f};
#pragma unroll
    for (int reg = 0; reg < 4; ++reg) m_[mi][reg] = -1e30f;
  }

  for (int kt = 0; kt < nt; ++kt) {
    const int sb = sbeg + kt * 32;
    const bool lastt = (sb == q0);  // only the diagonal tile needs masking

    f32x4 s[2][2];
#pragma unroll
    for (int mi = 0; mi < 2; ++mi)
#pragma unroll
      for (int ni = 0; ni < 2; ++ni) s[mi][ni] = (f32x4){0.f, 0.f, 0.f, 0.f};
#pragma unroll
    for (int ni = 0; ni < 2; ++ni) {
      short8 kf[4];
#pragma unroll
      for (int kk = 0; kk < 4; ++kk)
        kf[kk] = *(const short8*)&Kb[(sb + ni * 16 + l15) * DH_ + kk * 32 + lg * 8];
#pragma unroll
      for (int mi = 0; mi < 2; ++mi)
#pragma unroll
        for (int kk = 0; kk < 4; ++kk)
          s[mi][ni] = MFMA16(qf[mi][kk], kf[kk], s[mi][ni]);
    }

    // hoist V loads over softmax (latency hides under the reduce)
    short8 vf[8];
#pragma unroll
    for (int di = 0; di < 8; ++di)
      vf[di] = *(const short8*)&Vb[(di * 16 + l15) * S_ + sb + lg * 8];

#pragma unroll
    for (int mi = 0; mi < 2; ++mi) {
      float alpha[4];
#pragma unroll
      for (int reg = 0; reg < 4; ++reg) {
        int q = q0 + mi * 16 + lg * 4 + reg;
        float v0 = s[mi][0][reg];
        float v1 = s[mi][1][reg];
        if (lastt) {
          if (sb + l15 > q)      v0 = -1e30f;
          if (sb + 16 + l15 > q) v1 = -1e30f;
        }
        float rmax = fmaxf(v0, v1);
#pragma unroll
        for (int d = 1; d < 16; d <<= 1) rmax = fmaxf(rmax, __shfl_xor(rmax, d));
        float mn = fmaxf(m_[mi][reg], rmax);
        alpha[reg] = exp2f(m_[mi][reg] - mn);
        m_[mi][reg] = mn;
        float p0 = exp2f(v0 - mn), p1 = exp2f(v1 - mn);
        plds[w][mi][lg * 4 + reg][l15]      = f2bf(p0);
        plds[w][mi][lg * 4 + reg][16 + l15] = f2bf(p1);
      }
#pragma unroll
      for (int di = 0; di < 8; ++di)
#pragma unroll
        for (int reg = 0; reg < 4; ++reg) of[mi][di][reg] *= alpha[reg];
#pragma unroll
      for (int reg = 0; reg < 4; ++reg) l_acc[mi][reg] *= alpha[reg];
    }

    short8 pa[2];
#pragma unroll
    for (int mi = 0; mi < 2; ++mi)
      pa[mi] = *(const short8*)&plds[w][mi][l15][lg * 8];

#pragma unroll
    for (int di = 0; di < 8; ++di)
#pragma unroll
      for (int mi = 0; mi < 2; ++mi) of[mi][di] = MFMA16(pa[mi], vf[di], of[mi][di]);
    // row sums via ones-B MFMA (replaces 32-swizzle sum chain)
#pragma unroll
    for (int mi = 0; mi < 2; ++mi) l_acc[mi] = MFMA16(pa[mi], ones, l_acc[mi]);
  }

  // partial epilogue: normalized fp16 O + (m, l)
  unsigned short* op = Opart + g * 4096;
  float* mlg = ml + g * 64;
#pragma unroll
  for (int mi = 0; mi < 2; ++mi)
#pragma unroll
    for (int reg = 0; reg < 4; ++reg) {
      int row = mi * 16 + lg * 4 + reg;
      float inv = 1.0f / l_acc[mi][reg];
#pragma unroll
      for (int di = 0; di < 8; ++di)
        op[row * 128 + di * 16 + l15] = f2h(of[mi][di][reg] * inv);
      if (l15 == 0) {
        mlg[row * 2]     = m_[mi][reg];
        mlg[row * 2 + 1] = l_acc[mi][reg];
      }
    }
}

// ---------------- K2b: combine partials -> O bf16 ----------------
// grid 2048 = (bh, qw); block 256: thread = (row=tid>>3, d0=(tid&7)*16)
__global__ void k_combine(const unsigned short* __restrict__ Opart,
                          const float* __restrict__ ml,
                          unsigned short* __restrict__ O) {
  const int bh = blockIdx.x >> 5, qw = blockIdx.x & 31;
  const int nc = (qw >> 3) + 1;
  const int rbase = (qw < 8)  ? qw
                  : (qw < 16) ? 8 + 2 * (qw - 8)
                  : (qw < 24) ? 24 + 3 * (qw - 16)
                              : 48 + 4 * (qw - 24);
  const int g0 = bh * 80 + rbase;
  const int tid = threadIdx.x;
  const int row = tid >> 3, d0 = (tid & 7) * 16;

  float m[4], l[4];
  float mx = -1e30f;
  for (int i = 0; i < nc; ++i) {
    m[i] = ml[(g0 + i) * 64 + row * 2];
    l[i] = ml[(g0 + i) * 64 + row * 2 + 1];
    mx = fmaxf(mx, m[i]);
  }
  float wt[4], wsum = 0.f;
  for (int i = 0; i < nc; ++i) { wt[i] = l[i] * exp2f(m[i] - mx); wsum += wt[i]; }
  float invw = 1.0f / wsum;

  float acc[16];
#pragma unroll
  for (int j = 0; j < 16; ++j) acc[j] = 0.f;
  for (int i = 0; i < nc; ++i) {
    const unsigned short* op = Opart + (g0 + i) * 4096 + row * 128 + d0;
    float w = wt[i];
#pragma unroll
    for (int j = 0; j < 16; ++j) acc[j] += w * h2f(op[j]);
  }

  const int b = bh >> 3, h = bh & 7;
  const int q = qw * 32 + row;
  unsigned short* dst = O + (b * S_ + q) * DM_ + h * DH_ + d0;
  short8 o0, o1;
#pragma unroll
  for (int j = 0; j < 8; ++j) { o0[j] = (short)f2bf(acc[j] * invw); o1[j] = (short)f2bf(acc[8 + j] * invw); }
  *(short8*)&dst[0] = o0;
  *(short8*)&dst[8] = o1;
}

// ---------------- K2-fallback: single-pass causal flash attention ----------------
__global__ __launch_bounds__(256) void k_attn(
    const unsigned short* __restrict__ Qp, const unsigned short* __restrict__ Kp,
    const unsigned short* __restrict__ VpT, unsigned short* __restrict__ O) {
  __shared__ __align__(16) unsigned short plds[4][2][16][40];

  const int qt = 7 - blockIdx.x;
  const int bh = blockIdx.y;
  const int tid = threadIdx.x, lane = tid & 63, w = tid >> 6;
  const int l15 = lane & 15, lg = lane >> 4;
  const int q0 = qt * 128 + w * 32;

  const unsigned short* Qb = Qp + bh * (S_ * DH_);
  const unsigned short* Kb = Kp + bh * (S_ * DH_);
  const unsigned short* Vb = VpT + bh * (DH_ * S_);

  short8 qf[2][4];
#pragma unroll
  for (int mi = 0; mi < 2; ++mi)
#pragma unroll
    for (int kk = 0; kk < 4; ++kk)
      qf[mi][kk] = *(const short8*)&Qb[(q0 + mi * 16 + l15) * DH_ + kk * 32 + lg * 8];

  f32x4 of[2][8];
  float m_[2][4], l_[2][4];
#pragma unroll
  for (int mi = 0; mi < 2; ++mi) {
#pragma unroll
    for (int di = 0; di < 8; ++di) of[mi][di] = (f32x4){0.f, 0.f, 0.f, 0.f};
#pragma unroll
    for (int reg = 0; reg < 4; ++reg) { m_[mi][reg] = -1e30f; l_[mi][reg] = 0.f; }
  }

  const int ntiles = q0 / 32 + 1;
  for (int kt = 0; kt < ntiles; ++kt) {
    const int sb = kt * 32;
    const bool lastt = (kt == ntiles - 1);

    f32x4 s[2][2];
#pragma unroll
    for (int mi = 0; mi < 2; ++mi)
#pragma unroll
      for (int ni = 0; ni < 2; ++ni) s[mi][ni] = (f32x4){0.f, 0.f, 0.f, 0.f};
#pragma unroll
    for (int ni = 0; ni < 2; ++ni) {
      short8 kf[4];
#pragma unroll
      for (int kk = 0; kk < 4; ++kk)
        kf[kk] = *(const short8*)&Kb[(sb + ni * 16 + l15) * DH_ + kk * 32 + lg * 8];
#pragma unroll
      for (int mi = 0; mi < 2; ++mi)
#pragma unroll
        for (int kk = 0; kk < 4; ++kk)
          s[mi][ni] = MFMA16(qf[mi][kk], kf[kk], s[mi][ni]);
    }

#pragma unroll
    for (int mi = 0; mi < 2; ++mi) {
      float alpha[4];
#pragma unroll
      for (int reg = 0; reg < 4; ++reg) {
        int q = q0 + mi * 16 + lg * 4 + reg;
        float v0 = s[mi][0][reg];
        float v1 = s[mi][1][reg];
        if (lastt) {
          if (sb + l15 > q)      v0 = -1e30f;
          if (sb + 16 + l15 > q) v1 = -1e30f;
        }
        float rmax = fmaxf(v0, v1);
#pragma unroll
        for (int d = 1; d < 16; d <<= 1) rmax = fmaxf(rmax, __shfl_xor(rmax, d));
        float mn = fmaxf(m_[mi][reg], rmax);
        alpha[reg] = exp2f(m_[mi][reg] - mn);
        m_[mi][reg] = mn;
        float p0 = exp2f(v0 - mn), p1 = exp2f(v1 - mn);
        float rs = p0 + p1;
#pragma unroll
        for (int d = 1; d < 16; d <<= 1) rs += __shfl_xor(rs, d);
        l_[mi][reg] = l_[mi][reg] * alpha[reg] + rs;
        plds[w][mi][lg * 4 + reg][l15]      = f2bf(p0);
        plds[w][mi][lg * 4 + reg][16 + l15] = f2bf(p1);
      }
#pragma unroll
      for (int di = 0; di < 8; ++di)
#pragma unroll
        for (int reg = 0; reg < 4; ++reg) of[mi][di][reg] *= alpha[reg];
    }

    short8 pa[2];
#pragma unroll
    for (int mi = 0; mi < 2; ++mi)
      pa[mi] = *(const short8*)&plds[w][mi][l15][lg * 8];

#pragma unroll
    for (int di = 0; di < 8; ++di) {
      short8 vf = *(const short8*)&Vb[(di * 16 + l15) * S_ + sb + lg * 8];
#pragma unroll
      for (int mi = 0; mi < 2; ++mi) of[mi][di] = MFMA16(pa[mi], vf, of[mi][di]);
    }
  }

  const int b = bh >> 3, h = bh & 7;
#pragma unroll
  for (int mi = 0; mi < 2; ++mi)
#pragma unroll
    for (int reg = 0; reg < 4; ++reg) {
      float inv = 1.0f / l_[mi][reg];
      int q = q0 + mi * 16 + lg * 4 + reg;
#pragma unroll
      for (int di = 0; di < 8; ++di) {
        int d = di * 16 + l15;
        O[(b * S_ + q) * DM_ + h * DH_ + d] = f2bf(of[mi][di][reg] * inv);
      }
    }
}

// ---------------- K3: out-proj split-K GEMM ----------------
__global__ __launch_bounds__(256) void k_oproj(
    const unsigned short* __restrict__ O, const unsigned short* __restrict__ WoT,
    float* __restrict__ outacc) {
  const int tid = threadIdx.x, lane = tid & 63, wave = tid >> 6;
  const int wm = wave >> 1, wn = wave & 1;
  const int l15 = lane & 15, lg = lane >> 4;
  const int mbase = blockIdx.x * 128 + wm * 64;
  const int kc = blockIdx.y;

  f32x4 acc[4][4];
#pragma unroll
  for (int mi = 0; mi < 4; ++mi)
#pragma unroll
    for (int ni = 0; ni < 4; ++ni) acc[mi][ni] = (f32x4){0.f, 0.f, 0.f, 0.f};

  for (int ks = 0; ks < 8; ++ks) {
    int kb = kc * 256 + ks * 32;
    short8 a[4], bfr[4];
#pragma unroll
    for (int mi = 0; mi < 4; ++mi)
      a[mi] = *(const short8*)&O[(mbase + mi * 16 + l15) * DM_ + kb + lg * 8];
#pragma unroll
    for (int ni = 0; ni < 4; ++ni)
      bfr[ni] = *(const short8*)&WoT[(wn * 64 + ni * 16 + l15) * DM_ + kb + lg * 8];
#pragma unroll
    for (int mi = 0; mi < 4; ++mi)
#pragma unroll
      for (int ni = 0; ni < 4; ++ni) acc[mi][ni] = MFMA16(a[mi], bfr[ni], acc[mi][ni]);
  }

  float* oa = outacc + kc * (8192 * 128);
#pragma unroll
  for (int mi = 0; mi < 4; ++mi)
#pragma unroll
    for (int ni = 0; ni < 4; ++ni) {
      int n = wn * 64 + ni * 16 + l15;
#pragma unroll
      for (int reg = 0; reg < 4; ++reg) {
        int m = mbase + mi * 16 + lg * 4 + reg;
        oa[m * 128 + n] = acc[mi][ni][reg];
      }
    }
}

// ---------------- K4: reduce split-K + bias -> out ----------------
__global__ void k_final(const float* __restrict__ outacc,
                        const unsigned short* __restrict__ boc,
                        const int* __restrict__ flag, void* __restrict__ out) {
  int i4 = (blockIdx.x * 256 + threadIdx.x) * 4;
  f32x4 v = *(const f32x4*)&outacc[i4];
  v += *(const f32x4*)&outacc[1048576 + i4];
  v += *(const f32x4*)&outacc[2097152 + i4];
  v += *(const f32x4*)&outacc[3145728 + i4];
  int n0 = i4 & 127;
#pragma unroll
  for (int j = 0; j < 4; ++j) v[j] += bf2f(boc[n0 + j]);
  if (*flag) {
    *(f32x4*)&((float*)out)[i4] = v;
  } else {
    short4v o;
#pragma unroll
    for (int j = 0; j < 4; ++j) o[j] = (short)f2bf(v[j]);
    *(short4v*)&((unsigned short*)out)[i4] = o;
  }
}

extern "C" void kernel_launch(void* const* d_in, const int* in_sizes, int n_in,
                              void* d_out, int out_size, void* d_ws, size_t ws_size,
                              hipStream_t stream) {
  const void* q  = d_in[0];
  const void* k  = d_in[1];
  const void* v  = d_in[2];
  const void* Wq = d_in[3];
  const void* bq = d_in[4];
  const void* Wk = d_in[5];
  const void* bk = d_in[6];
  const void* Wv = d_in[7];
  const void* bv = d_in[8];
  const void* Wo = d_in[9];
  const void* bo = d_in[10];

  char* ws = (char*)d_ws;
  int*            flag = (int*)(ws + 0);
  unsigned short* wqT  = (unsigned short*)(ws + 4096);
  unsigned short* wkT  = (unsigned short*)(ws + 266240);
  unsigned short* wvT  = (unsigned short*)(ws + 528384);
  unsigned short* woT  = (unsigned short*)(ws + 790528);
  unsigned short* bqc  = (unsigned short*)(ws + 1052672);
  unsigned short* bkc  = (unsigned short*)(ws + 1054720);
  unsigned short* bvc  = (unsigned short*)(ws + 1056768);
  unsigned short* boc  = (unsigned short*)(ws + 1058816);
  unsigned short* Xq   = (unsigned short*)(ws + 2097152);   // 2 MB (ml aliases later)
  unsigned short* Xk   = (unsigned short*)(ws + 4194304);
  unsigned short* Xv   = (unsigned short*)(ws + 6291456);
  unsigned short* Qp   = (unsigned short*)(ws + 8388608);   // 16 MB
  unsigned short* Kp   = (unsigned short*)(ws + 25165824);  // 16 MB
  unsigned short* VpT  = (unsigned short*)(ws + 41943040);  // 16 MB
  unsigned short* O    = (unsigned short*)(ws + 58720256);  // 16 MB
  float*          oacc = (float*)(ws + 75497472);           // 16 MB (aliases Opart head)
  unsigned short* Opart= (unsigned short*)(ws + 75497472);  // 40 MB fp16 partials
  float*          ml   = (float*)(ws + 2097152);            // 1.31 MB (aliases dead Xq)

  const bool use_split = ws_size >= (size_t)117440512;  // Opart end

  k_detect<<<dim3(1), 256, 0, stream>>>((const unsigned short*)q, flag);
  k_cvt_x<<<dim3(1024, 3), 256, 0, stream>>>(q, k, v, flag, Xq, Xk, Xv);
  k_cvt_w<<<dim3(2061), 256, 0, stream>>>(Wq, Wk, Wv, Wo, bq, bk, bv, bo, flag,
                                          wqT, wkT, wvT, woT, bqc, bkc, bvc, boc);
  k_qkv<<<dim3(64, 8, 3), 256, 0, stream>>>(Xq, Xk, Xv, wqT, wkT, wvT, bqc, bkc, bvc,
                                            Qp, Kp, VpT);
  if (use_split) {
    k_attn_split<<<dim3(1280), 256, 0, stream>>>(Qp, Kp, VpT, Opart, ml);
    k_combine<<<dim3(2048), 256, 0, stream>>>(Opart, ml, O);
  } else {
    k_attn<<<dim3(8, 64), 256, 0, stream>>>(Qp, Kp, VpT, O);
  }
  k_oproj<<<dim3(64, 4), 256, 0, stream>>>(O, woT, oacc);
  k_final<<<dim3(1024), 256, 0, stream>>>(oacc, boc, flag, d_out);
}

// Round 5
// 183.526 us; speedup vs baseline: 1.4178x; 1.0603x over previous
//
#include <hip/hip_runtime.h>
#include <hip/hip_bf16.h>

// MultiheadAttention: B=8, T=S=1024, n_heads=8, d_head=128, D=1024.
// Pipeline: detect dtype -> cvt to bf16 -> QKV proj GEMM -> split-S flash
// attention (defer-max softmax, XCD-chunked swizzle, balanced blocks) ->
// combine -> out-proj split-K -> reduce+bias.

typedef __attribute__((ext_vector_type(8))) short short8;
typedef __attribute__((ext_vector_type(4))) short short4v;
typedef __attribute__((ext_vector_type(4))) float f32x4;

#define B_   8
#define S_   1024
#define DH_  128
#define NH_  8
#define DM_  1024

#define MFMA16(a, b, c) __builtin_amdgcn_mfma_f32_16x16x32_bf16((a), (b), (c), 0, 0, 0)

__device__ __forceinline__ float bf2f(unsigned short u) {
  union { unsigned int i; float f; } x; x.i = ((unsigned int)u) << 16; return x.f;
}
__device__ __forceinline__ unsigned short f2bf(float f) {
  union { float f; unsigned int i; } x; x.f = f;
  unsigned int r = (x.i + 0x7fffu + ((x.i >> 16) & 1u)) >> 16;
  return (unsigned short)r;
}
__device__ __forceinline__ unsigned short f2h(float f) {
  union { _Float16 h; unsigned short u; } x; x.h = (_Float16)f; return x.u;
}
__device__ __forceinline__ float h2f(unsigned short u) {
  union { unsigned short u; _Float16 h; } x; x.u = u; return (float)x.h;
}
__device__ __forceinline__ float ldany(const void* p, int i, int fp) {
  return fp ? ((const float*)p)[i] : bf2f(((const unsigned short*)p)[i]);
}

// ---------------- D: input dtype detection ----------------
__global__ void k_detect(const unsigned short* __restrict__ in, int* __restrict__ flag) {
  __shared__ int f;
  int tid = threadIdx.x;
  if (tid == 0) f = 0;
  __syncthreads();
  int t = 0;
  for (int i = tid; i < 16384; i += 256) {
    unsigned h = in[i];
    unsigned e = (h >> 7) & 0xFFu, m = h & 0x7Fu;
    if (e == 0xFFu || (e == 0u && m != 0u)) t = 1;
  }
  if (t) atomicOr(&f, 1);
  __syncthreads();
  if (tid == 0) *flag = f;  // 1 = fp32, 0 = bf16
}

// ---------------- C1: q/k/v -> canonical bf16 (x4 vectorized) ----------------
__global__ void k_cvt_x(const void* __restrict__ q, const void* __restrict__ k,
                        const void* __restrict__ v, const int* __restrict__ flag,
                        unsigned short* __restrict__ Xq, unsigned short* __restrict__ Xk,
                        unsigned short* __restrict__ Xv) {
  const int fp = *flag;
  int z = blockIdx.y;
  const void* in = (z == 0) ? q : (z == 1) ? k : v;
  unsigned short* out = (z == 0) ? Xq : (z == 1) ? Xk : Xv;
  int e4 = (blockIdx.x * 256 + threadIdx.x) * 4;
  if (fp) {
    f32x4 x = *(const f32x4*)&((const float*)in)[e4];
    short4v o;
#pragma unroll
    for (int j = 0; j < 4; ++j) o[j] = (short)f2bf(x[j]);
    *(short4v*)&out[e4] = o;
  } else {
    *(short4v*)&out[e4] = *(const short4v*)&((const unsigned short*)in)[e4];
  }
}

// ---------------- C2: weights (transposed) + biases -> canonical bf16 ----------------
__global__ void k_cvt_w(const void* __restrict__ Wq, const void* __restrict__ Wk,
                        const void* __restrict__ Wv, const void* __restrict__ Wo,
                        const void* __restrict__ bq, const void* __restrict__ bk,
                        const void* __restrict__ bv, const void* __restrict__ bo,
                        const int* __restrict__ flag,
                        unsigned short* __restrict__ wqT, unsigned short* __restrict__ wkT,
                        unsigned short* __restrict__ wvT, unsigned short* __restrict__ woT,
                        unsigned short* __restrict__ bqc, unsigned short* __restrict__ bkc,
                        unsigned short* __restrict__ bvc, unsigned short* __restrict__ boc) {
  const int fp = *flag;
  int g = blockIdx.x * 256 + threadIdx.x;
  if (g < 393216) {
    int z = g >> 17, e = g & 131071;
    const void* in = (z == 0) ? Wq : (z == 1) ? Wk : Wv;
    unsigned short* out = (z == 0) ? wqT : (z == 1) ? wkT : wvT;
    int r = e >> 10, c = e & 1023;
    out[c * 128 + r] = f2bf(ldany(in, e, fp));
  } else if (g < 524288) {
    int e = g - 393216;
    int r = e >> 7, c = e & 127;
    woT[c * 1024 + r] = f2bf(ldany(Wo, e, fp));
  } else if (g < 525312) {
    int e = g - 524288; bqc[e] = f2bf(ldany(bq, e, fp));
  } else if (g < 526336) {
    int e = g - 525312; bkc[e] = f2bf(ldany(bk, e, fp));
  } else if (g < 527360) {
    int e = g - 526336; bvc[e] = f2bf(ldany(bv, e, fp));
  } else if (g < 527488) {
    int e = g - 527360; boc[e] = f2bf(ldany(bo, e, fp));
  }
}

// ---------------- K1: fused QKV projection GEMM ----------------
__global__ __launch_bounds__(256) void k_qkv(
    const unsigned short* __restrict__ Xq, const unsigned short* __restrict__ Xk,
    const unsigned short* __restrict__ Xv,
    const unsigned short* __restrict__ WqT, const unsigned short* __restrict__ WkT,
    const unsigned short* __restrict__ WvT,
    const unsigned short* __restrict__ bq, const unsigned short* __restrict__ bk,
    const unsigned short* __restrict__ bv,
    unsigned short* __restrict__ Qp, unsigned short* __restrict__ Kp,
    unsigned short* __restrict__ VpT) {
  __shared__ unsigned short vtile[128][136];

  const int mat = blockIdx.z;
  const unsigned short* X    = (mat == 0) ? Xq  : (mat == 1) ? Xk  : Xv;
  const unsigned short* WT   = (mat == 0) ? WqT : (mat == 1) ? WkT : WvT;
  const unsigned short* bias = (mat == 0) ? bq  : (mat == 1) ? bk  : bv;
  const float scale = (mat == 0) ? (1.4426950408889634f / 11.313708498984761f) : 1.0f;

  const int tid = threadIdx.x, lane = tid & 63, wave = tid >> 6;
  const int wm = wave >> 1, wn = wave & 1;
  const int l15 = lane & 15, lg = lane >> 4;
  const int mbase = blockIdx.x * 128 + wm * 64;
  const int nbase = blockIdx.y * 128 + wn * 64;

  short8 a[4][4];
#pragma unroll
  for (int mi = 0; mi < 4; ++mi)
#pragma unroll
    for (int kk = 0; kk < 4; ++kk)
      a[mi][kk] = *(const short8*)&X[(mbase + mi * 16 + l15) * DH_ + kk * 32 + lg * 8];

  f32x4 acc[4][4];
#pragma unroll
  for (int mi = 0; mi < 4; ++mi)
#pragma unroll
    for (int ni = 0; ni < 4; ++ni) acc[mi][ni] = (f32x4){0.f, 0.f, 0.f, 0.f};

#pragma unroll
  for (int ni = 0; ni < 4; ++ni) {
    short8 bfr[4];
#pragma unroll
    for (int kk = 0; kk < 4; ++kk)
      bfr[kk] = *(const short8*)&WT[(nbase + ni * 16 + l15) * DH_ + kk * 32 + lg * 8];
#pragma unroll
    for (int mi = 0; mi < 4; ++mi)
#pragma unroll
      for (int kk = 0; kk < 4; ++kk)
        acc[mi][ni] = MFMA16(a[mi][kk], bfr[kk], acc[mi][ni]);
  }

  if (mat < 2) {
    unsigned short* Out = (mat == 0) ? Qp : Kp;
#pragma unroll
    for (int mi = 0; mi < 4; ++mi)
#pragma unroll
      for (int ni = 0; ni < 4; ++ni) {
        int n = nbase + ni * 16 + l15;
        float bv_ = bf2f(bias[n]);
        int h = n >> 7, dh = n & 127;
#pragma unroll
        for (int reg = 0; reg < 4; ++reg) {
          int m = mbase + mi * 16 + lg * 4 + reg;
          int b = m >> 10, t = m & 1023;
          float val = (acc[mi][ni][reg] + bv_) * scale;
          Out[((b * NH_ + h) * S_ + t) * DH_ + dh] = f2bf(val);
        }
      }
  } else {
#pragma unroll
    for (int mi = 0; mi < 4; ++mi)
#pragma unroll
      for (int ni = 0; ni < 4; ++ni) {
        int nl = wn * 64 + ni * 16 + l15;
        float bv_ = bf2f(bias[blockIdx.y * 128 + nl]);
#pragma unroll
        for (int reg = 0; reg < 4; ++reg) {
          int ml_ = wm * 64 + mi * 16 + lg * 4 + reg;
          vtile[ml_][nl] = f2bf(acc[mi][ni][reg] + bv_);
        }
      }
    __syncthreads();
    int n = tid >> 1;
    int thalf = (tid & 1) * 64;
    int b = blockIdx.x >> 3;
    int h = blockIdx.y;
    int base = ((b * NH_ + h) * DH_ + n) * S_ + (blockIdx.x & 7) * 128 + thalf;
#pragma unroll
    for (int jj = 0; jj < 8; ++jj) {
      short8 v;
#pragma unroll
      for (int j2 = 0; j2 < 8; ++j2) v[j2] = (short)vtile[thalf + jj * 8 + j2][n];
      *(short8*)&VpT[base + jj * 8] = v;
    }
  }
}

// ---------------- K2: split-S causal flash attention ----------------
// 1280 blocks x 4 waves = 5120 units: (bh, qw, s-chunk of <=256).
// XCD-chunked swizzle (8 bh per XCD -> K/V L2-resident); block-balanced unit
// permutation {j,39-j,40+j,79-j}; defer-max softmax (skip rescale+shuffle
// chain unless max grew by >8); ones-MFMA row sums; nc==1 writes O directly.
__global__ __launch_bounds__(256) void k_attn_split(
    const unsigned short* __restrict__ Qp, const unsigned short* __restrict__ Kp,
    const unsigned short* __restrict__ VpT,
    unsigned short* __restrict__ Opart, float* __restrict__ ml,
    unsigned short* __restrict__ O) {
  __shared__ __align__(16) unsigned short plds[4][2][16][44];

  const int tid = threadIdx.x, lane = tid & 63, w = tid >> 6;
  const int l15 = lane & 15, lg = lane >> 4;

  // XCD-chunked swizzle: XCD x gets blocks [x*160, (x+1)*160) = 8 bh
  const int bid = blockIdx.x;
  const int swz = (bid & 7) * 160 + (bid >> 3);
  const int bh = swz / 20;
  const int j = swz % 20;
  // balanced unit permutation within bh
  const int r = (w == 0) ? j : (w == 1) ? (39 - j) : (w == 2) ? (40 + j) : (79 - j);

  int qw, c;
  if (r < 8)       { qw = r;                   c = 0; }
  else if (r < 24) { qw = 8 + ((r - 8) >> 1);  c = (r - 8) & 1; }
  else if (r < 48) { qw = 16 + (r - 24) / 3;   c = (r - 24) % 3; }
  else             { qw = 24 + ((r - 48) >> 2); c = (r - 48) & 3; }
  const int q0 = qw * 32;
  const int nc = (qw >> 3) + 1;
  const int sbeg = c * 256;
  const int send = (c == nc - 1) ? (q0 + 32) : (sbeg + 256);
  const int nt = (send - sbeg) >> 5;

  const unsigned short* Qb = Qp + bh * (S_ * DH_);
  const unsigned short* Kb = Kp + bh * (S_ * DH_);
  const unsigned short* Vb = VpT + bh * (DH_ * S_);

  short8 qf[2][4];
#pragma unroll
  for (int mi = 0; mi < 2; ++mi)
#pragma unroll
    for (int kk = 0; kk < 4; ++kk)
      qf[mi][kk] = *(const short8*)&Qb[(q0 + mi * 16 + l15) * DH_ + kk * 32 + lg * 8];

  short8 ones;
#pragma unroll
  for (int jj = 0; jj < 8; ++jj) ones[jj] = (short)0x3F80;  // bf16 1.0

  f32x4 of[2][8], l_acc[2];
  float m_[2][4];
#pragma unroll
  for (int mi = 0; mi < 2; ++mi) {
#pragma unroll
    for (int di = 0; di < 8; ++di) of[mi][di] = (f32x4){0.f, 0.f, 0.f, 0.f};
    l_acc[mi] = (f32x4){0.f, 0.f, 0.f, 0.f};
#pragma unroll
    for (int reg = 0; reg < 4; ++reg) m_[mi][reg] = -1e30f;
  }

  for (int kt = 0; kt < nt; ++kt) {
    const int sb = sbeg + kt * 32;
    const bool lastt = (sb == q0);

    f32x4 s[2][2];
#pragma unroll
    for (int mi = 0; mi < 2; ++mi)
#pragma unroll
      for (int ni = 0; ni < 2; ++ni) s[mi][ni] = (f32x4){0.f, 0.f, 0.f, 0.f};
#pragma unroll
    for (int ni = 0; ni < 2; ++ni) {
      short8 kf[4];
#pragma unroll
      for (int kk = 0; kk < 4; ++kk)
        kf[kk] = *(const short8*)&Kb[(sb + ni * 16 + l15) * DH_ + kk * 32 + lg * 8];
#pragma unroll
      for (int mi = 0; mi < 2; ++mi)
#pragma unroll
        for (int kk = 0; kk < 4; ++kk)
          s[mi][ni] = MFMA16(qf[mi][kk], kf[kk], s[mi][ni]);
    }

    // V loads issued before softmax -> latency hides under the VALU chain
    short8 vf[8];
#pragma unroll
    for (int di = 0; di < 8; ++di)
      vf[di] = *(const short8*)&Vb[(di * 16 + l15) * S_ + sb + lg * 8];

    // mask diagonal tile
    if (lastt) {
#pragma unroll
      for (int mi = 0; mi < 2; ++mi)
#pragma unroll
        for (int reg = 0; reg < 4; ++reg) {
          int q = q0 + mi * 16 + lg * 4 + reg;
          if (sb + l15 > q)      s[mi][0][reg] = -1e30f;
          if (sb + 16 + l15 > q) s[mi][1][reg] = -1e30f;
        }
    }

    // defer-max: only rescale when some row's max grew past m_ + 8
    bool need = false;
    float vmax[2][4];
#pragma unroll
    for (int mi = 0; mi < 2; ++mi)
#pragma unroll
      for (int reg = 0; reg < 4; ++reg) {
        vmax[mi][reg] = fmaxf(s[mi][0][reg], s[mi][1][reg]);
        need |= (vmax[mi][reg] > m_[mi][reg] + 8.0f);
      }
    if (__any(need)) {
#pragma unroll
      for (int mi = 0; mi < 2; ++mi) {
        float alpha[4];
#pragma unroll
        for (int reg = 0; reg < 4; ++reg) {
          float rmax = vmax[mi][reg];
#pragma unroll
          for (int d = 1; d < 16; d <<= 1) rmax = fmaxf(rmax, __shfl_xor(rmax, d));
          float mn = fmaxf(m_[mi][reg], rmax);
          alpha[reg] = exp2f(m_[mi][reg] - mn);
          m_[mi][reg] = mn;
        }
#pragma unroll
        for (int di = 0; di < 8; ++di)
#pragma unroll
          for (int reg = 0; reg < 4; ++reg) of[mi][di][reg] *= alpha[reg];
#pragma unroll
        for (int reg = 0; reg < 4; ++reg) l_acc[mi][reg] *= alpha[reg];
      }
    }

#pragma unroll
    for (int mi = 0; mi < 2; ++mi)
#pragma unroll
      for (int reg = 0; reg < 4; ++reg) {
        float p0 = exp2f(s[mi][0][reg] - m_[mi][reg]);
        float p1 = exp2f(s[mi][1][reg] - m_[mi][reg]);
        plds[w][mi][lg * 4 + reg][l15]      = f2bf(p0);
        plds[w][mi][lg * 4 + reg][16 + l15] = f2bf(p1);
      }

    short8 pa[2];
#pragma unroll
    for (int mi = 0; mi < 2; ++mi)
      pa[mi] = *(const short8*)&plds[w][mi][l15][lg * 8];

#pragma unroll
    for (int di = 0; di < 8; ++di)
#pragma unroll
      for (int mi = 0; mi < 2; ++mi) of[mi][di] = MFMA16(pa[mi], vf[di], of[mi][di]);
#pragma unroll
    for (int mi = 0; mi < 2; ++mi) l_acc[mi] = MFMA16(pa[mi], ones, l_acc[mi]);
  }

  if (nc == 1) {
    // whole row done: write O directly, skip partials
    const int b = bh >> 3, h = bh & 7;
#pragma unroll
    for (int mi = 0; mi < 2; ++mi)
#pragma unroll
      for (int reg = 0; reg < 4; ++reg) {
        int row = mi * 16 + lg * 4 + reg;
        float inv = 1.0f / l_acc[mi][reg];
        int q = q0 + row;
#pragma unroll
        for (int di = 0; di < 8; ++di)
          O[(b * S_ + q) * DM_ + h * DH_ + di * 16 + l15] = f2bf(of[mi][di][reg] * inv);
      }
  } else {
    const int g = bh * 80 + r;
    unsigned short* op = Opart + g * 4096;
    float* mlg = ml + g * 64;
#pragma unroll
    for (int mi = 0; mi < 2; ++mi)
#pragma unroll
      for (int reg = 0; reg < 4; ++reg) {
        int row = mi * 16 + lg * 4 + reg;
        float inv = 1.0f / l_acc[mi][reg];
#pragma unroll
        for (int di = 0; di < 8; ++di)
          op[row * 128 + di * 16 + l15] = f2h(of[mi][di][reg] * inv);
        if (l15 == 0) {
          mlg[row * 2]     = m_[mi][reg];
          mlg[row * 2 + 1] = l_acc[mi][reg];
        }
      }
  }
}

// ---------------- K2b: combine partials (qw >= 8 only) -> O bf16 ----------------
// grid 1536 = 64 bh x 24 qw; block 256: thread = (row=tid>>3, d0=(tid&7)*16)
__global__ void k_combine(const unsigned short* __restrict__ Opart,
                          const float* __restrict__ ml,
                          unsigned short* __restrict__ O) {
  const int bh = blockIdx.x / 24, qw = 8 + blockIdx.x % 24;
  const int nc = (qw >> 3) + 1;  // 2..4
  const int rbase = (qw < 16) ? 8 + 2 * (qw - 8)
                  : (qw < 24) ? 24 + 3 * (qw - 16)
                              : 48 + 4 * (qw - 24);
  const int g0 = bh * 80 + rbase;
  const int tid = threadIdx.x;
  const int row = tid >> 3, d0 = (tid & 7) * 16;

  float m[4], l[4];
  float mx = -1e30f;
  for (int i = 0; i < nc; ++i) {
    m[i] = ml[(g0 + i) * 64 + row * 2];
    l[i] = ml[(g0 + i) * 64 + row * 2 + 1];
    mx = fmaxf(mx, m[i]);
  }
  float wt[4], wsum = 0.f;
  for (int i = 0; i < nc; ++i) { wt[i] = l[i] * exp2f(m[i] - mx); wsum += wt[i]; }
  float invw = 1.0f / wsum;

  float acc[16];
#pragma unroll
  for (int jj = 0; jj < 16; ++jj) acc[jj] = 0.f;
  for (int i = 0; i < nc; ++i) {
    const unsigned short* op = Opart + (g0 + i) * 4096 + row * 128 + d0;
    float w = wt[i];
#pragma unroll
    for (int jj = 0; jj < 16; ++jj) acc[jj] += w * h2f(op[jj]);
  }

  const int b = bh >> 3, h = bh & 7;
  const int q = qw * 32 + row;
  unsigned short* dst = O + (b * S_ + q) * DM_ + h * DH_ + d0;
  short8 o0, o1;
#pragma unroll
  for (int jj = 0; jj < 8; ++jj) {
    o0[jj] = (short)f2bf(acc[jj] * invw);
    o1[jj] = (short)f2bf(acc[8 + jj] * invw);
  }
  *(short8*)&dst[0] = o0;
  *(short8*)&dst[8] = o1;
}

// ---------------- K2-fallback: single-pass causal flash attention ----------------
__global__ __launch_bounds__(256) void k_attn(
    const unsigned short* __restrict__ Qp, const unsigned short* __restrict__ Kp,
    const unsigned short* __restrict__ VpT, unsigned short* __restrict__ O) {
  __shared__ __align__(16) unsigned short plds[4][2][16][44];

  const int qt = 7 - blockIdx.x;
  const int bh = blockIdx.y;
  const int tid = threadIdx.x, lane = tid & 63, w = tid >> 6;
  const int l15 = lane & 15, lg = lane >> 4;
  const int q0 = qt * 128 + w * 32;

  const unsigned short* Qb = Qp + bh * (S_ * DH_);
  const unsigned short* Kb = Kp + bh * (S_ * DH_);
  const unsigned short* Vb = VpT + bh * (DH_ * S_);

  short8 qf[2][4];
#pragma unroll
  for (int mi = 0; mi < 2; ++mi)
#pragma unroll
    for (int kk = 0; kk < 4; ++kk)
      qf[mi][kk] = *(const short8*)&Qb[(q0 + mi * 16 + l15) * DH_ + kk * 32 + lg * 8];

  f32x4 of[2][8];
  float m_[2][4], l_[2][4];
#pragma unroll
  for (int mi = 0; mi < 2; ++mi) {
#pragma unroll
    for (int di = 0; di < 8; ++di) of[mi][di] = (f32x4){0.f, 0.f, 0.f, 0.f};
#pragma unroll
    for (int reg = 0; reg < 4; ++reg) { m_[mi][reg] = -1e30f; l_[mi][reg] = 0.f; }
  }

  const int ntiles = q0 / 32 + 1;
  for (int kt = 0; kt < ntiles; ++kt) {
    const int sb = kt * 32;
    const bool lastt = (kt == ntiles - 1);

    f32x4 s[2][2];
#pragma unroll
    for (int mi = 0; mi < 2; ++mi)
#pragma unroll
      for (int ni = 0; ni < 2; ++ni) s[mi][ni] = (f32x4){0.f, 0.f, 0.f, 0.f};
#pragma unroll
    for (int ni = 0; ni < 2; ++ni) {
      short8 kf[4];
#pragma unroll
      for (int kk = 0; kk < 4; ++kk)
        kf[kk] = *(const short8*)&Kb[(sb + ni * 16 + l15) * DH_ + kk * 32 + lg * 8];
#pragma unroll
      for (int mi = 0; mi < 2; ++mi)
#pragma unroll
        for (int kk = 0; kk < 4; ++kk)
          s[mi][ni] = MFMA16(qf[mi][kk], kf[kk], s[mi][ni]);
    }

#pragma unroll
    for (int mi = 0; mi < 2; ++mi) {
      float alpha[4];
#pragma unroll
      for (int reg = 0; reg < 4; ++reg) {
        int q = q0 + mi * 16 + lg * 4 + reg;
        float v0 = s[mi][0][reg];
        float v1 = s[mi][1][reg];
        if (lastt) {
          if (sb + l15 > q)      v0 = -1e30f;
          if (sb + 16 + l15 > q) v1 = -1e30f;
        }
        float rmax = fmaxf(v0, v1);
#pragma unroll
        for (int d = 1; d < 16; d <<= 1) rmax = fmaxf(rmax, __shfl_xor(rmax, d));
        float mn = fmaxf(m_[mi][reg], rmax);
        alpha[reg] = exp2f(m_[mi][reg] - mn);
        m_[mi][reg] = mn;
        float p0 = exp2f(v0 - mn), p1 = exp2f(v1 - mn);
        float rs = p0 + p1;
#pragma unroll
        for (int d = 1; d < 16; d <<= 1) rs += __shfl_xor(rs, d);
        l_[mi][reg] = l_[mi][reg] * alpha[reg] + rs;
        plds[w][mi][lg * 4 + reg][l15]      = f2bf(p0);
        plds[w][mi][lg * 4 + reg][16 + l15] = f2bf(p1);
      }
#pragma unroll
      for (int di = 0; di < 8; ++di)
#pragma unroll
        for (int reg = 0; reg < 4; ++reg) of[mi][di][reg] *= alpha[reg];
    }

    short8 pa[2];
#pragma unroll
    for (int mi = 0; mi < 2; ++mi)
      pa[mi] = *(const short8*)&plds[w][mi][l15][lg * 8];

#pragma unroll
    for (int di = 0; di < 8; ++di) {
      short8 vf = *(const short8*)&Vb[(di * 16 + l15) * S_ + sb + lg * 8];
#pragma unroll
      for (int mi = 0; mi < 2; ++mi) of[mi][di] = MFMA16(pa[mi], vf, of[mi][di]);
    }
  }

  const int b = bh >> 3, h = bh & 7;
#pragma unroll
  for (int mi = 0; mi < 2; ++mi)
#pragma unroll
    for (int reg = 0; reg < 4; ++reg) {
      float inv = 1.0f / l_[mi][reg];
      int q = q0 + mi * 16 + lg * 4 + reg;
#pragma unroll
      for (int di = 0; di < 8; ++di) {
        int d = di * 16 + l15;
        O[(b * S_ + q) * DM_ + h * DH_ + d] = f2bf(of[mi][di][reg] * inv);
      }
    }
}

// ---------------- K3: out-proj split-K GEMM ----------------
__global__ __launch_bounds__(256) void k_oproj(
    const unsigned short* __restrict__ O, const unsigned short* __restrict__ WoT,
    float* __restrict__ outacc) {
  const int tid = threadIdx.x, lane = tid & 63, wave = tid >> 6;
  const int wm = wave >> 1, wn = wave & 1;
  const int l15 = lane & 15, lg = lane >> 4;
  const int mbase = blockIdx.x * 128 + wm * 64;
  const int kc = blockIdx.y;

  f32x4 acc[4][4];
#pragma unroll
  for (int mi = 0; mi < 4; ++mi)
#pragma unroll
    for (int ni = 0; ni < 4; ++ni) acc[mi][ni] = (f32x4){0.f, 0.f, 0.f, 0.f};

  for (int ks = 0; ks < 8; ++ks) {
    int kb = kc * 256 + ks * 32;
    short8 a[4], bfr[4];
#pragma unroll
    for (int mi = 0; mi < 4; ++mi)
      a[mi] = *(const short8*)&O[(mbase + mi * 16 + l15) * DM_ + kb + lg * 8];
#pragma unroll
    for (int ni = 0; ni < 4; ++ni)
      bfr[ni] = *(const short8*)&WoT[(wn * 64 + ni * 16 + l15) * DM_ + kb + lg * 8];
#pragma unroll
    for (int mi = 0; mi < 4; ++mi)
#pragma unroll
      for (int ni = 0; ni < 4; ++ni) acc[mi][ni] = MFMA16(a[mi], bfr[ni], acc[mi][ni]);
  }

  float* oa = outacc + kc * (8192 * 128);
#pragma unroll
  for (int mi = 0; mi < 4; ++mi)
#pragma unroll
    for (int ni = 0; ni < 4; ++ni) {
      int n = wn * 64 + ni * 16 + l15;
#pragma unroll
      for (int reg = 0; reg < 4; ++reg) {
        int m = mbase + mi * 16 + lg * 4 + reg;
        oa[m * 128 + n] = acc[mi][ni][reg];
      }
    }
}

// ---------------- K4: reduce split-K + bias -> out ----------------
__global__ void k_final(const float* __restrict__ outacc,
                        const unsigned short* __restrict__ boc,
                        const int* __restrict__ flag, void* __restrict__ out) {
  int i4 = (blockIdx.x * 256 + threadIdx.x) * 4;
  f32x4 v = *(const f32x4*)&outacc[i4];
  v += *(const f32x4*)&outacc[1048576 + i4];
  v += *(const f32x4*)&outacc[2097152 + i4];
  v += *(const f32x4*)&outacc[3145728 + i4];
  int n0 = i4 & 127;
#pragma unroll
  for (int j = 0; j < 4; ++j) v[j] += bf2f(boc[n0 + j]);
  if (*flag) {
    *(f32x4*)&((float*)out)[i4] = v;
  } else {
    short4v o;
#pragma unroll
    for (int j = 0; j < 4; ++j) o[j] = (short)f2bf(v[j]);
    *(short4v*)&((unsigned short*)out)[i4] = o;
  }
}

extern "C" void kernel_launch(void* const* d_in, const int* in_sizes, int n_in,
                              void* d_out, int out_size, void* d_ws, size_t ws_size,
                              hipStream_t stream) {
  const void* q  = d_in[0];
  const void* k  = d_in[1];
  const void* v  = d_in[2];
  const void* Wq = d_in[3];
  const void* bq = d_in[4];
  const void* Wk = d_in[5];
  const void* bk = d_in[6];
  const void* Wv = d_in[7];
  const void* bv = d_in[8];
  const void* Wo = d_in[9];
  const void* bo = d_in[10];

  char* ws = (char*)d_ws;
  int*            flag = (int*)(ws + 0);
  unsigned short* wqT  = (unsigned short*)(ws + 4096);
  unsigned short* wkT  = (unsigned short*)(ws + 266240);
  unsigned short* wvT  = (unsigned short*)(ws + 528384);
  unsigned short* woT  = (unsigned short*)(ws + 790528);
  unsigned short* bqc  = (unsigned short*)(ws + 1052672);
  unsigned short* bkc  = (unsigned short*)(ws + 1054720);
  unsigned short* bvc  = (unsigned short*)(ws + 1056768);
  unsigned short* boc  = (unsigned short*)(ws + 1058816);
  unsigned short* Xq   = (unsigned short*)(ws + 2097152);   // 2 MB (ml aliases later)
  unsigned short* Xk   = (unsigned short*)(ws + 4194304);
  unsigned short* Xv   = (unsigned short*)(ws + 6291456);
  unsigned short* Qp   = (unsigned short*)(ws + 8388608);   // 16 MB
  unsigned short* Kp   = (unsigned short*)(ws + 25165824);  // 16 MB
  unsigned short* VpT  = (unsigned short*)(ws + 41943040);  // 16 MB
  unsigned short* O    = (unsigned short*)(ws + 58720256);  // 16 MB
  float*          oacc = (float*)(ws + 75497472);           // 16 MB (aliases Opart head)
  unsigned short* Opart= (unsigned short*)(ws + 75497472);  // 40 MB fp16 partials
  float*          ml   = (float*)(ws + 2097152);            // 1.31 MB (aliases dead Xq)

  const bool use_split = ws_size >= (size_t)117440512;

  k_detect<<<dim3(1), 256, 0, stream>>>((const unsigned short*)q, flag);
  k_cvt_x<<<dim3(1024, 3), 256, 0, stream>>>(q, k, v, flag, Xq, Xk, Xv);
  k_cvt_w<<<dim3(2061), 256, 0, stream>>>(Wq, Wk, Wv, Wo, bq, bk, bv, bo, flag,
                                          wqT, wkT, wvT, woT, bqc, bkc, bvc, boc);
  k_qkv<<<dim3(64, 8, 3), 256, 0, stream>>>(Xq, Xk, Xv, wqT, wkT, wvT, bqc, bkc, bvc,
                                            Qp, Kp, VpT);
  if (use_split) {
    k_attn_split<<<dim3(1280), 256, 0, stream>>>(Qp, Kp, VpT, Opart, ml, O);
    k_combine<<<dim3(1536), 256, 0, stream>>>(Opart, ml, O);
  } else {
    k_attn<<<dim3(8, 64), 256, 0, stream>>>(Qp, Kp, VpT, O);
  }
  k_oproj<<<dim3(64, 4), 256, 0, stream>>>(O, woT, oacc);
  k_final<<<dim3(1024), 256, 0, stream>>>(oacc, boc, flag, d_out);
}